// Round 11
// baseline (383.671 us; speedup 1.0000x reference)
//
#include <hip/hip_runtime.h>
#include <math.h>

#define NEG_SLOPE 0.2f
#define FIN 128
#define H1 8
#define F1 64   // HEADS1*HID
#define F1P 68  // padded a1s row stride (floats): conflict-free epilogue b128 reads
#define F2 32   // OUT2

#define SHIFT 5
#define BW 32          // dsts per bucket
#define CAPL 2048      // LDS edge slots per bucket (mean ~1056, sigma ~32)
#define CAP_G 1408     // static pk slots per bucket (mean+11sigma)
#define NBMAX 4096

// two-pass radix partition (write-coalescing fix for the 7x write amplification)
#define SB_SHIFT 11            // 2048 nodes per super-bucket = 64 final buckets
#define NSBMAX 64              // supports N <= 131072
#define P_CHUNK 2048           // edges per partition block
#define BPS 35                 // pass-2 blocks per SB
#define SBCAP (BPS * P_CHUNK)  // slots per SB in sbdata

typedef unsigned short ushort_t;
typedef unsigned int uint_t;

#define LO16(u) __uint_as_float((u) << 16)
#define HI16(u) __uint_as_float((u) & 0xffff0000u)

// fold across the 4 edge slots (lane bits 4..5) -- R3-proven edge1 shape
#define FOLDQ4(x) { x += __shfl_xor(x, 16, 64); x += __shfl_xor(x, 32, 64); }
// fold across all 64 lanes (leaves the TOTAL in every lane -- lane-uniform!)
#define FOLD64(x) { x += __shfl_xor(x, 1, 64); x += __shfl_xor(x, 2, 64); x += __shfl_xor(x, 4, 64); \
                    x += __shfl_xor(x, 8, 64); x += __shfl_xor(x, 16, 64); x += __shfl_xor(x, 32, 64); }

static __device__ __forceinline__ ushort_t f2bf(float f) {
    uint_t u = __float_as_uint(f);
    u = (u + 0x7FFFu + ((u >> 16) & 1u)) >> 16; // RNE
    return (ushort_t)u;
}
// pack {A=exp(e), B=exp(0.2e)} as bf16x2: A in low 16, B in high 16
static __device__ __forceinline__ uint_t packAB(float e) {
    return (uint_t)f2bf(__expf(e)) | ((uint_t)f2bf(__expf(NEG_SLOPE * e)) << 16);
}

// ---------------- Layer-1 GEMM: h1 = x @ W1 (bf16 out), fused exp-tables -----
__global__ void gemm1_kernel(const float* __restrict__ x, const float* __restrict__ W1,
                             const float* __restrict__ a_src, const float* __restrict__ a_dst,
                             ushort_t* __restrict__ h1, uint_t* __restrict__ sp,
                             float* __restrict__ ed, int N) {
    __shared__ float xs[16][FIN]; // 8 KB
    int tid = threadIdx.x;
    int n0 = blockIdx.x * 16;
    for (int i = tid; i < 16 * FIN; i += 256) {
        int nn = n0 + (i >> 7);
        xs[i >> 7][i & 127] = (nn < N) ? x[(size_t)nn * FIN + (i & 127)] : 0.f;
    }
    __syncthreads();
    int wv = tid >> 6, j = tid & 63;
    int nb = wv << 2;
    float a0 = 0.f, a1 = 0.f, a2 = 0.f, a3 = 0.f;
#pragma unroll 2
    for (int k = 0; k < FIN; k += 4) {
        float w0 = W1[(k + 0) * F1 + j];
        float w1 = W1[(k + 1) * F1 + j];
        float w2 = W1[(k + 2) * F1 + j];
        float w3 = W1[(k + 3) * F1 + j];
        float4 x0 = *(const float4*)&xs[nb + 0][k];
        float4 x1 = *(const float4*)&xs[nb + 1][k];
        float4 x2 = *(const float4*)&xs[nb + 2][k];
        float4 x3 = *(const float4*)&xs[nb + 3][k];
        a0 = fmaf(x0.x, w0, fmaf(x0.y, w1, fmaf(x0.z, w2, fmaf(x0.w, w3, a0))));
        a1 = fmaf(x1.x, w0, fmaf(x1.y, w1, fmaf(x1.z, w2, fmaf(x1.w, w3, a1))));
        a2 = fmaf(x2.x, w0, fmaf(x2.y, w1, fmaf(x2.z, w2, fmaf(x2.w, w3, a2))));
        a3 = fmaf(x3.x, w0, fmaf(x3.y, w1, fmaf(x3.z, w2, fmaf(x3.w, w3, a3))));
    }
    float as = a_src[j], ad = a_dst[j];
    float av[4] = {a0, a1, a2, a3};
#pragma unroll
    for (int t = 0; t < 4; ++t) {
        int n = n0 + nb + t;
        if (n >= N) break;
        h1[(size_t)n * F1 + j] = f2bf(av[t]);
        float vs = av[t] * as;
        float vd = av[t] * ad;
#pragma unroll
        for (int off = 4; off >= 1; off >>= 1) {
            vs += __shfl_down(vs, off, 8);
            vd += __shfl_down(vd, off, 8);
        }
        if ((j & 7) == 0) {
            sp[n * H1 + (j >> 3)] = packAB(vs);
            ed[n * H1 + (j >> 3)] = vd;
        }
    }
}

// ---------------- init ------------------------------------------------------
__global__ void zerob_kernel(int* __restrict__ bcnt, int* __restrict__ boff,
                             int NB, float* __restrict__ pooled, int capg,
                             int* __restrict__ sbcnt, int nsb) {
    int t = blockIdx.x * blockDim.x + threadIdx.x;
    int stride = gridDim.x * blockDim.x;
    for (int i = t; i < NB; i += stride) {
        bcnt[i] = 0;
        if (capg) boff[i] = i * capg;
    }
    for (int i = t; i < nsb; i += stride) sbcnt[i] = 0;
    if (t == 0) pooled[0] = 0.f;
}

// ---------------- Pass 1: partition edges into super-buckets (coalesced) -----
// Per-wave split histograms/cursors: 4x less LDS-atomic contention.
__global__ void __launch_bounds__(256, 4)
part1_kernel(const int* __restrict__ ei, int E, int N,
             int* __restrict__ sbcnt, uint_t* __restrict__ sbdata) {
    __shared__ int histw[4][NSBMAX];
    __shared__ int lcurw[4][NSBMAX];
    __shared__ int loff[NSBMAX];
    __shared__ int gb[NSBMAX];
    __shared__ uint_t buf[P_CHUNK];
    __shared__ unsigned char sbarr[P_CHUNK];
    int tid = threadIdx.x;
    int wv = tid >> 6;
    int NSB = (N + ((1 << SB_SHIFT) - 1)) >> SB_SHIFT;
    for (int i = tid; i < 4 * NSBMAX; i += 256) ((int*)histw)[i] = 0;
    __syncthreads();
    int EN = E + N;
    int base = blockIdx.x * P_CHUNK;
    int m = EN - base; if (m > P_CHUNK) m = P_CHUNK;
    int t0 = base + tid * 8;
    int s[8], d[8];
    bool fast = (t0 + 8 <= E) && ((E & 3) == 0);
    if (fast) {
        int4 a = *(const int4*)&ei[t0];
        int4 b = *(const int4*)&ei[t0 + 4];
        s[0]=a.x; s[1]=a.y; s[2]=a.z; s[3]=a.w; s[4]=b.x; s[5]=b.y; s[6]=b.z; s[7]=b.w;
        int4 c = *(const int4*)&ei[E + t0];
        int4 e2 = *(const int4*)&ei[E + t0 + 4];
        d[0]=c.x; d[1]=c.y; d[2]=c.z; d[3]=c.w; d[4]=e2.x; d[5]=e2.y; d[6]=e2.z; d[7]=e2.w;
    } else {
#pragma unroll
        for (int r = 0; r < 8; ++r) {
            int t = t0 + r;
            if (t < EN) {
                if (t < E) { s[r] = ei[t]; d[r] = ei[E + t]; }
                else       { s[r] = d[r] = t - E; }
            } else d[r] = -1;
        }
    }
#pragma unroll
    for (int r = 0; r < 8; ++r)
        if (d[r] >= 0) atomicAdd(&histw[wv][d[r] >> SB_SHIFT], 1);
    __syncthreads();
    if (tid < 64) {
        int h0 = 0, h1 = 0, h2 = 0, h3 = 0;
        if (tid < NSB) {
            h0 = histw[0][tid]; h1 = histw[1][tid];
            h2 = histw[2][tid]; h3 = histw[3][tid];
        }
        int tot = h0 + h1 + h2 + h3;
        int e = tot;
#pragma unroll
        for (int o = 1; o < 64; o <<= 1) {
            int u = __shfl_up(e, o, 64);
            if (tid >= o) e += u;
        }
        e -= tot; // exclusive prefix
        if (tid < NSB) {
            loff[tid] = e;
            gb[tid] = tot ? atomicAdd(&sbcnt[tid], tot) : 0;
            lcurw[0][tid] = e;
            lcurw[1][tid] = e + h0;
            lcurw[2][tid] = e + h0 + h1;
            lcurw[3][tid] = e + h0 + h1 + h2;
        }
    }
    __syncthreads();
#pragma unroll
    for (int r = 0; r < 8; ++r)
        if (d[r] >= 0) {
            int sb = d[r] >> SB_SHIFT;
            int pos = atomicAdd(&lcurw[wv][sb], 1);
            buf[pos] = ((uint_t)s[r] << SB_SHIFT) | (uint_t)(d[r] & ((1 << SB_SHIFT) - 1));
            sbarr[pos] = (unsigned char)sb;
        }
    __syncthreads();
    for (int i = tid; i < m; i += 256) {
        int sb = sbarr[i];
        int idx = gb[sb] + (i - loff[sb]);
        if (idx < SBCAP)
            sbdata[(size_t)sb * SBCAP + idx] = buf[i];
    }
}

// ---------------- Pass 2: scatter within SB to final pk buckets (coalesced) --
__global__ void __launch_bounds__(256, 4)
part2_kernel(const uint_t* __restrict__ sbdata, const int* __restrict__ sbcnt,
             int* __restrict__ bcnt, const int* __restrict__ boff,
             uint_t* __restrict__ pk) {
    __shared__ int histw[4][64];
    __shared__ int lcurw[4][64];
    __shared__ int loff[64];
    __shared__ int gb[64];
    __shared__ uint_t buf[P_CHUNK];
    int tid = threadIdx.x;
    int wv = tid >> 6;
    int sb = blockIdx.x / BPS;
    int base = (blockIdx.x % BPS) * P_CHUNK;
    int cnt = sbcnt[sb];
    if (cnt > SBCAP) cnt = SBCAP;
    if (base >= cnt) return;
    int m = cnt - base; if (m > P_CHUNK) m = P_CHUNK;
    for (int i = tid; i < 4 * 64; i += 256) ((int*)histw)[i] = 0;
    __syncthreads();
    const uint_t* src = sbdata + (size_t)sb * SBCAP + base;
    uint_t v[8];
#pragma unroll
    for (int r = 0; r < 8; ++r) {
        int i = tid + r * 256; // coalesced strided read
        if (i < m) {
            v[r] = src[i];
            atomicAdd(&histw[wv][(v[r] >> 5) & 63], 1);
        }
    }
    __syncthreads();
    if (tid < 64) {
        int h0 = histw[0][tid], h1 = histw[1][tid];
        int h2 = histw[2][tid], h3 = histw[3][tid];
        int tot = h0 + h1 + h2 + h3;
        int e = tot;
#pragma unroll
        for (int o = 1; o < 64; o <<= 1) {
            int u = __shfl_up(e, o, 64);
            if (tid >= o) e += u;
        }
        e -= tot;
        loff[tid] = e;
        int bucket = (sb << 6) + tid;
        gb[tid] = tot ? (boff[bucket] + atomicAdd(&bcnt[bucket], tot)) : 0;
        lcurw[0][tid] = e;
        lcurw[1][tid] = e + h0;
        lcurw[2][tid] = e + h0 + h1;
        lcurw[3][tid] = e + h0 + h1 + h2;
    }
    __syncthreads();
#pragma unroll
    for (int r = 0; r < 8; ++r) {
        int i = tid + r * 256;
        if (i < m) {
            int lb = (v[r] >> 5) & 63;
            int pos = atomicAdd(&lcurw[wv][lb], 1);
            buf[pos] = v[r];
        }
    }
    __syncthreads();
    for (int i = tid; i < m; i += 256) {
        uint_t u = buf[i];
        int lb = (u >> 5) & 63;
        int idx = gb[lb] + (i - loff[lb]);
        pk[idx] = ((u >> SB_SHIFT) << SHIFT) | (u & (BW - 1));
    }
}

// ---- exact-CSR fallback path (used only when ws_size too small for static) --
__global__ void bhist_kernel(const int* __restrict__ ei, int E, int N,
                             int* __restrict__ bcnt, int NB) {
    __shared__ int h[NBMAX];
    int tid = threadIdx.x;
    for (int i = tid; i < NB; i += 256) h[i] = 0;
    __syncthreads();
    int EN = E + N;
    int chunk = (EN + gridDim.x - 1) / gridDim.x;
    int e0 = blockIdx.x * chunk;
    int e1 = e0 + chunk; if (e1 > EN) e1 = EN;
    for (int t = e0 + tid; t < e1; t += 256) {
        int d = (t < E) ? ei[E + t] : (t - E);
        atomicAdd(&h[d >> SHIFT], 1);
    }
    __syncthreads();
    for (int i = tid; i < NB; i += 256)
        if (h[i]) atomicAdd(&bcnt[i], h[i]);
}

__global__ void bscan_kernel(const int* __restrict__ bcnt, int NB,
                             int* __restrict__ boff, int* __restrict__ bcur) {
    int lane = threadIdx.x; // 0..63
    int chunk = (NB + 63) >> 6;
    int lo = lane * chunk;
    int hi = lo + chunk; if (hi > NB) hi = NB;
    int sum = 0;
    for (int i = lo; i < hi; ++i) sum += bcnt[i];
    int e = sum;
#pragma unroll
    for (int o = 1; o < 64; o <<= 1) {
        int v = __shfl_up(e, o, 64);
        if (lane >= o) e += v;
    }
    e -= sum;
    int run = e;
    for (int i = lo; i < hi; ++i) {
        int c = bcnt[i];
        boff[i] = run;
        bcur[i] = run;
        run += c;
    }
}

__global__ void bscat_kernel(const int* __restrict__ ei, int E, int N,
                             int* __restrict__ bcur, uint_t* __restrict__ pk, int NB) {
    __shared__ int lh[NBMAX];
    __shared__ int lc[NBMAX];
    int tid = threadIdx.x;
    for (int i = tid; i < NB; i += 256) lh[i] = 0;
    __syncthreads();
    int EN = E + N;
    int chunk = (EN + gridDim.x - 1) / gridDim.x;
    int e0 = blockIdx.x * chunk;
    int e1 = e0 + chunk; if (e1 > EN) e1 = EN;
    for (int t = e0 + tid; t < e1; t += 256) {
        int d = (t < E) ? ei[E + t] : (t - E);
        atomicAdd(&lh[d >> SHIFT], 1);
    }
    __syncthreads();
    for (int i = tid; i < NB; i += 256) {
        int c = lh[i];
        lc[i] = c ? atomicAdd(&bcur[i], c) : 0;
    }
    __syncthreads();
    for (int t = e0 + tid; t < e1; t += 256) {
        int s, d;
        if (t < E) { s = ei[t]; d = ei[E + t]; } else { s = d = t - E; }
        int pos = atomicAdd(&lc[d >> SHIFT], 1);
        pk[pos] = ((uint_t)s << SHIFT) | (uint_t)(d & (BW - 1));
    }
}

// ---------------- Fused layer-1 edge pass + layer-2 GEMM ---------------------
// Gather body is the R3/R8-proven one. R11 changes vs R10:
//  (a) build uses per-wave split histograms/cursors (4x less LDS-atomic clash),
//  (b) epilogue GEMM vectorized: thread=(row, j-quad), b128 a1 reads (padded
//      row stride F1P -> conflict-free), float4 W2 loads, no redundant passes.
__global__ void __launch_bounds__(256, 8)
edge1_fused(const int* __restrict__ bcnt, const int* __restrict__ boff,
            uint_t* __restrict__ pk,
            const uint_t* __restrict__ sp, const float* __restrict__ ed,
            const ushort_t* __restrict__ h1,
            const float* __restrict__ b1, const float* __restrict__ W2,
            const float* __restrict__ a_src2, const float* __restrict__ a_dst2,
            const float* __restrict__ Wr,
            uint2* __restrict__ rec, float* __restrict__ ed2,
            int* __restrict__ loffg, int* __restrict__ ldegg, int N) {
    int b = blockIdx.x;
    int d0 = b << SHIFT;
    int cnt = bcnt[b];
    int gbase = boff[b];
    int tid = threadIdx.x;
    int wv = tid >> 6;
    int L = tid & 63;
    int q = L >> 4;           // edge slot 0..3
    int c4 = (L & 15) << 2;   // channel base
    int hL = (L & 15) >> 1;   // head of channels c4..c4+3
    __shared__ int ldeg[BW], loff[BW];
    __shared__ int ldegw[4][BW], lcurw[4][BW];
    __shared__ int lsrc[CAPL];
    __shared__ float a1s[BW][F1P];  // padded rows: epilogue b128 conflict-free
    if (cnt <= CAPL) {
        for (int i = tid; i < 4 * BW; i += 256) ((int*)ldegw)[i] = 0;
        __syncthreads();
        for (int k = tid; k < cnt; k += 256)
            atomicAdd(&ldegw[wv][pk[gbase + k] & (BW - 1)], 1);
        __syncthreads();
        if (tid < BW) {
            int h0 = ldegw[0][tid], h1_ = ldegw[1][tid];
            int h2 = ldegw[2][tid], h3 = ldegw[3][tid];
            int v = h0 + h1_ + h2 + h3;
            int e = v;
#pragma unroll
            for (int o = 1; o < BW; o <<= 1) {
                int u = __shfl_up(e, o, 64);
                if (tid >= o) e += u;
            }
            e -= v;
            loff[tid] = e;
            ldeg[tid] = v;
            lcurw[0][tid] = e;
            lcurw[1][tid] = e + h0;
            lcurw[2][tid] = e + h0 + h1_;
            lcurw[3][tid] = e + h0 + h1_ + h2;
        }
        __syncthreads();
        for (int k = tid; k < cnt; k += 256) {
            uint_t v = pk[gbase + k];
            int pos = atomicAdd(&lcurw[wv][v & (BW - 1)], 1);
            lsrc[pos] = (int)(v >> SHIFT);
        }
        __syncthreads();
        // writeback for edge2: pk becomes the dst-sorted src list; per-dst CSR
        for (int k = tid; k < cnt; k += 256) pk[gbase + k] = (uint_t)lsrc[k];
        if (tid < BW) {
            loffg[d0 + tid] = loff[tid];
            ldegg[d0 + tid] = ldeg[tid];
        }
        for (int ld = wv * 8; ld < wv * 8 + 8; ++ld) {
            int d = d0 + ld;
            if (d >= N) break;
            int st = loff[ld], en = st + ldeg[ld];
            float edv = ed[d * H1 + hL];
            float Ad = __expf(edv), Bd = __expf(NEG_SLOPE * edv);
            float ax = 0.f, ay = 0.f, az = 0.f, aw = 0.f, wsum = 0.f;
            uint_t U0, U1; uint2 V0, V1;
            {
                int i0 = st + q, i1 = st + 4 + q;
                bool ok0 = i0 < en, ok1 = i1 < en;
                int s0 = lsrc[ok0 ? i0 : st];   // st valid: self-loop => en>st
                int s1 = lsrc[ok1 ? i1 : st];
                uint_t u0 = sp[s0 * H1 + hL];
                uint_t u1 = sp[s1 * H1 + hL];
                V0 = *(const uint2*)(h1 + ((size_t)s0 << 6) + c4);
                V1 = *(const uint2*)(h1 + ((size_t)s1 << 6) + c4);
                U0 = ok0 ? u0 : 0u;
                U1 = ok1 ? u1 : 0u;
            }
            for (int k = st; k < en; k += 8) {
                uint_t N0, N1; uint2 P0, P1;
                {
                    int i0 = k + 8 + q, i1 = k + 12 + q;
                    bool ok0 = i0 < en, ok1 = i1 < en;
                    int s0 = lsrc[ok0 ? i0 : st];
                    int s1 = lsrc[ok1 ? i1 : st];
                    uint_t u0 = sp[s0 * H1 + hL];
                    uint_t u1 = sp[s1 * H1 + hL];
                    P0 = *(const uint2*)(h1 + ((size_t)s0 << 6) + c4);
                    P1 = *(const uint2*)(h1 + ((size_t)s1 << 6) + c4);
                    N0 = ok0 ? u0 : 0u;
                    N1 = ok1 ? u1 : 0u;
                }
                float w0 = fmaxf(LO16(U0) * Ad, HI16(U0) * Bd);
                float w1 = fmaxf(LO16(U1) * Ad, HI16(U1) * Bd);
                ax = fmaf(w0, LO16(V0.x), ax);
                ay = fmaf(w0, HI16(V0.x), ay);
                az = fmaf(w0, LO16(V0.y), az);
                aw = fmaf(w0, HI16(V0.y), aw);
                ax = fmaf(w1, LO16(V1.x), ax);
                ay = fmaf(w1, HI16(V1.x), ay);
                az = fmaf(w1, LO16(V1.y), az);
                aw = fmaf(w1, HI16(V1.y), aw);
                wsum += w0 + w1;
                U0 = N0; U1 = N1; V0 = P0; V1 = P1;
            }
            FOLDQ4(ax); FOLDQ4(ay); FOLDQ4(az); FOLDQ4(aw); FOLDQ4(wsum);
            if (q == 0) {
                float inv = 1.f / wsum;
                a1s[ld][c4 + 0] = ax * inv;
                a1s[ld][c4 + 1] = ay * inv;
                a1s[ld][c4 + 2] = az * inv;
                a1s[ld][c4 + 3] = aw * inv;
            }
        }
    } else {
        // statistically unreachable fallback: masked whole-bucket scan
        for (int ld = wv * 8; ld < wv * 8 + 8; ++ld) {
            int d = d0 + ld;
            if (d >= N) break;
            float edv = ed[d * H1 + hL];
            float Ad = __expf(edv), Bd = __expf(NEG_SLOPE * edv);
            float ax = 0.f, ay = 0.f, az = 0.f, aw = 0.f, wsum = 0.f;
            for (int k0 = 0; k0 < cnt; k0 += 4) {
                int idx = k0 + q;
                bool ok = idx < cnt;
                uint_t v = pk[gbase + (ok ? idx : 0)];
                int s = (int)(v >> SHIFT);
                bool m = ok && ((int)(v & (BW - 1)) == ld);
                uint_t u = sp[(uint_t)s * H1 + hL];
                float w = m ? fmaxf(LO16(u) * Ad, HI16(u) * Bd) : 0.f;
                uint2 hv = *(const uint2*)(h1 + ((size_t)s << 6) + c4);
                ax = fmaf(w, LO16(hv.x), ax);
                ay = fmaf(w, HI16(hv.x), ay);
                az = fmaf(w, LO16(hv.y), az);
                aw = fmaf(w, HI16(hv.y), aw);
                wsum += w;
            }
            FOLDQ4(ax); FOLDQ4(ay); FOLDQ4(az); FOLDQ4(aw); FOLDQ4(wsum);
            if (q == 0) {
                float inv = 1.f / wsum;
                a1s[ld][c4 + 0] = ax * inv;
                a1s[ld][c4 + 1] = ay * inv;
                a1s[ld][c4 + 2] = az * inv;
                a1s[ld][c4 + 3] = aw * inv;
            }
        }
    }
    // -------- fused layer-2 GEMM epilogue (vectorized, R11) --------
    int nd = N - d0; if (nd > BW) nd = BW;  // valid dsts in this bucket
    __syncthreads();
    for (int i = tid; i < BW * F1; i += 256) {
        int dd = i >> 6;
        if (dd < nd) {
            int k = i & 63;
            float v = a1s[dd][k] + b1[k];
            a1s[dd][k] = v > 0.f ? v : expm1f(v); // ELU
        }
    }
    __syncthreads();
    // thread = (row, j-quad): row = tid>>3, jq = (tid&7)*4
    int row = tid >> 3;
    int jq = (tid & 7) << 2;
    if (row < nd) {
        float4 as2 = *(const float4*)&a_src2[jq];
        float4 ad2 = *(const float4*)&a_dst2[jq];
        float4 wr4 = *(const float4*)&Wr[jq];
        float c0 = 0.f, c1 = 0.f, c2 = 0.f, c3 = 0.f;
#pragma unroll
        for (int k = 0; k < F1; k += 4) {
            float4 a  = *(const float4*)&a1s[row][k];
            float4 w0 = *(const float4*)&W2[(k + 0) * F2 + jq];
            float4 w1 = *(const float4*)&W2[(k + 1) * F2 + jq];
            float4 w2 = *(const float4*)&W2[(k + 2) * F2 + jq];
            float4 w3 = *(const float4*)&W2[(k + 3) * F2 + jq];
            c0 = fmaf(a.x, w0.x, fmaf(a.y, w1.x, fmaf(a.z, w2.x, fmaf(a.w, w3.x, c0))));
            c1 = fmaf(a.x, w0.y, fmaf(a.y, w1.y, fmaf(a.z, w2.y, fmaf(a.w, w3.y, c1))));
            c2 = fmaf(a.x, w0.z, fmaf(a.y, w1.z, fmaf(a.z, w2.z, fmaf(a.w, w3.z, c2))));
            c3 = fmaf(a.x, w0.w, fmaf(a.y, w1.w, fmaf(a.z, w2.w, fmaf(a.w, w3.w, c3))));
        }
        float vs = c0 * as2.x + c1 * as2.y + c2 * as2.z + c3 * as2.w;
        float vd = c0 * ad2.x + c1 * ad2.y + c2 * ad2.z + c3 * ad2.w;
        float vg = c0 * wr4.x + c1 * wr4.y + c2 * wr4.z + c3 * wr4.w;
#pragma unroll
        for (int off = 4; off >= 1; off >>= 1) {
            vs += __shfl_down(vs, off, 8);
            vd += __shfl_down(vd, off, 8);
            vg += __shfl_down(vg, off, 8);
        }
        if ((tid & 7) == 0) {
            int d = d0 + row;
            uint2 r; r.x = packAB(vs); r.y = __float_as_uint(vg);
            rec[d] = r;
            ed2[d] = vd;
        }
    }
}

// ---------------- Layer-2 edge pass: pure streaming gather -------------------
// pk holds dst-sorted src lists (written by edge1_fused); loffg/ldegg give the
// per-dst CSR. No LDS build. Fallback buckets (cnt > CAPL) kept raw.
__global__ void __launch_bounds__(256, 8)
edge2_gather(const int* __restrict__ bcnt, const int* __restrict__ boff,
             const uint_t* __restrict__ pk,
             const int* __restrict__ loffg, const int* __restrict__ ldegg,
             const uint2* __restrict__ rec, const float* __restrict__ ed2,
             const float* __restrict__ b2, const float* __restrict__ Wr,
             float* __restrict__ pooled, int N) {
    int b = blockIdx.x;
    int d0 = b << SHIFT;
    int cnt = bcnt[b];
    int gbase = boff[b];
    int tid = threadIdx.x;
    int wv = tid >> 6;
    int L = tid & 63;
    __shared__ float ls[4];
    float t0 = (L < F2) ? b2[L] * Wr[L] : 0.f;
    FOLD64(t0);
    float b2w = t0;          // dot(b2, Wr), identical on all lanes
    float part = 0.f;
    if (cnt <= CAPL) {
        for (int ld = wv * 8; ld < wv * 8 + 8; ++ld) {
            int d = d0 + ld;
            if (d >= N) break;
            int st = gbase + loffg[d];
            int dg = ldegg[d];
            float edv = ed2[d];
            float Ad = __expf(edv), Bd = __expf(NEG_SLOPE * edv);
            float acc = 0.f, wsm = 0.f;
            for (int k = 0; k < dg; k += 64) {
                int i = k + L;
                bool ok = i < dg;
                int s = (int)pk[st + (ok ? i : 0)];
                uint2 r = rec[s];
                float w = ok ? fmaxf(LO16(r.x) * Ad, HI16(r.x) * Bd) : 0.f;
                acc = fmaf(w, __uint_as_float(r.y), acc);
                wsm += w;
            }
            FOLD64(acc); FOLD64(wsm);
            part += acc / wsm + b2w;   // FOLD64 left totals in EVERY lane
        }
    } else {
        // raw-pk masked scan (pk left in original packed format for this bucket)
        for (int ld = wv * 8; ld < wv * 8 + 8; ++ld) {
            int d = d0 + ld;
            if (d >= N) break;
            float edv = ed2[d];
            float Ad = __expf(edv), Bd = __expf(NEG_SLOPE * edv);
            float acc = 0.f, wsm = 0.f;
            for (int k0 = 0; k0 < cnt; k0 += 64) {
                int i = k0 + L;
                bool ok = i < cnt;
                uint_t v = pk[gbase + (ok ? i : 0)];
                int s = (int)(v >> SHIFT);
                bool mm = ok && ((int)(v & (BW - 1)) == ld);
                uint2 r = rec[s];
                float w = mm ? fmaxf(LO16(r.x) * Ad, HI16(r.x) * Bd) : 0.f;
                acc = fmaf(w, __uint_as_float(r.y), acc);
                wsm += w;
            }
            FOLD64(acc); FOLD64(wsm);
            part += acc / wsm + b2w;
        }
    }
    // part is LANE-UNIFORM (FOLD64 totals) -- take lane 0 only (R9 bug lesson).
    if (L == 0) ls[wv] = part;
    __syncthreads();
    if (tid == 0) atomicAdd(pooled, ls[0] + ls[1] + ls[2] + ls[3]);
}

__global__ void final_kernel(const float* __restrict__ pooled, const float* __restrict__ br,
                             float* __restrict__ out) {
    if (threadIdx.x == 0 && blockIdx.x == 0) out[0] = pooled[0] + br[0];
}

static inline size_t al128(size_t v) { return (v + 127) & ~(size_t)127; }

extern "C" void kernel_launch(void* const* d_in, const int* in_sizes, int n_in,
                              void* d_out, int out_size, void* d_ws, size_t ws_size,
                              hipStream_t stream) {
    const float* x    = (const float*)d_in[0];
    const int*   ei   = (const int*)d_in[1];
    const float* W1   = (const float*)d_in[2];
    const float* a_s1 = (const float*)d_in[3];
    const float* a_d1 = (const float*)d_in[4];
    const float* b1   = (const float*)d_in[5];
    const float* W2   = (const float*)d_in[6];
    const float* a_s2 = (const float*)d_in[7];
    const float* a_d2 = (const float*)d_in[8];
    const float* b2   = (const float*)d_in[9];
    const float* Wr   = (const float*)d_in[10];
    const float* br   = (const float*)d_in[11];
    float* out = (float*)d_out;

    int N = in_sizes[0] / FIN;
    int E = in_sizes[1] / 2;
    size_t n = (size_t)N;
    int NB = (N + BW - 1) >> SHIFT;
    int NSB = (N + ((1 << SB_SHIFT) - 1)) >> SB_SHIFT;

    // workspace layout (bytes); all hot arrays 128-B aligned.
    // CRITICAL: h1 rows are 128 B and gathered randomly -- h1 base MUST be
    // 128-aligned or every row straddles two cache lines (R4: FETCH +64%).
    char* ws = (char*)d_ws;
    size_t off_scr = 0;                                   // 256N scratch
    size_t off_sp1 = al128(off_scr + n * 256);            // 32N + 32
    size_t off_ed1 = al128(off_sp1 + n * 32 + 32);        // 32N
    size_t off_h1  = al128(off_ed1 + n * 32);             // 128N + 128
    size_t off_pk  = al128(off_h1 + n * 128 + 128);
    uint_t*   sp1  = (uint_t*)(ws + off_sp1);
    float*    ed1  = (float*)(ws + off_ed1);
    ushort_t* h1   = (ushort_t*)(ws + off_h1);
    uint_t*   pk   = (uint_t*)(ws + off_pk);
    size_t pk_static = (size_t)NB * CAP_G * 4;            // ~17.6 MB
    size_t pk_exact  = (size_t)(E + N) * 4;               // ~13.2 MB
    // scratch-region tenants (disjoint lifetimes):
    uint_t* sbdata = (uint_t*)(ws + off_scr);             // part1/part2 only
    size_t off_rec  = off_scr;                            // 8*NB*BW
    size_t off_ed2  = al128(off_rec + (size_t)NB * BW * 8);
    size_t off_lofg = al128(off_ed2 + (size_t)NB * BW * 4);
    size_t off_ldgg = al128(off_lofg + (size_t)NB * BW * 4);
    uint2* rec   = (uint2*)(ws + off_rec);
    float* ed2   = (float*)(ws + off_ed2);
    int*   loffg = (int*)(ws + off_lofg);
    int*   ldegg = (int*)(ws + off_ldgg);
    bool use_static = (NSB <= NSBMAX) &&
                      ((size_t)NSB * SBCAP * 4 <= n * 256) &&
                      (off_ldgg + (size_t)NB * BW * 4 <= n * 256) &&
                      (ws_size >= off_pk + pk_static + (size_t)NBMAX * 16 +
                                  (size_t)NSBMAX * 4 + 128);
    char* tail = ws + off_pk + (use_static ? pk_static : pk_exact);
    int*      bcnt  = (int*)tail;                         // NBMAX int
    int*      boff  = (int*)(tail + NBMAX * 4);           // NBMAX int
    int*      bcur  = (int*)(tail + NBMAX * 8);           // NBMAX int
    int*      sbcnt = (int*)(tail + NBMAX * 12);          // NSBMAX int
    float*  pooled  = (float*)(tail + NBMAX * 12 + NSBMAX * 4); // 1 f32

    zerob_kernel<<<8, 256, 0, stream>>>(bcnt, boff, NB, pooled,
                                        use_static ? CAP_G : 0, sbcnt, NSB);
    if (use_static) {
        int EN = E + N;
        int G1 = (EN + P_CHUNK - 1) / P_CHUNK;
        part1_kernel<<<G1, 256, 0, stream>>>(ei, E, N, sbcnt, sbdata);
        part2_kernel<<<NSB * BPS, 256, 0, stream>>>(sbdata, sbcnt, bcnt, boff, pk);
        gemm1_kernel<<<(N + 15) / 16, 256, 0, stream>>>(x, W1, a_s1, a_d1, h1, sp1, ed1, N);
    } else {
        gemm1_kernel<<<(N + 15) / 16, 256, 0, stream>>>(x, W1, a_s1, a_d1, h1, sp1, ed1, N);
        bhist_kernel<<<256, 256, 0, stream>>>(ei, E, N, bcnt, NB);
        bscan_kernel<<<1, 64, 0, stream>>>(bcnt, NB, boff, bcur);
        bscat_kernel<<<256, 256, 0, stream>>>(ei, E, N, bcur, pk, NB);
    }
    edge1_fused<<<NB, 256, 0, stream>>>(bcnt, boff, pk, sp1, ed1, h1,
                                        b1, W2, a_s2, a_d2, Wr,
                                        rec, ed2, loffg, ldegg, N);
    edge2_gather<<<NB, 256, 0, stream>>>(bcnt, boff, pk, loffg, ldegg,
                                         rec, ed2, b2, Wr, pooled, N);
    final_kernel<<<1, 64, 0, stream>>>(pooled, br, out);
}

// Round 12
// 372.251 us; speedup vs baseline: 1.0307x; 1.0307x over previous
//
#include <hip/hip_runtime.h>
#include <math.h>

#define NEG_SLOPE 0.2f
#define FIN 128
#define H1 8
#define F1 64   // HEADS1*HID
#define F2 32   // OUT2

#define SHIFT 5
#define BW 32          // dsts per bucket
#define CAPL 2048      // LDS edge slots per bucket (mean ~1056, sigma ~32)
#define CAP_G 1408     // static pk slots per bucket (mean+11sigma)
#define NBMAX 4096

// two-pass radix partition (write-coalescing fix for the 7x write amplification)
#define SB_SHIFT 11            // 2048 nodes per super-bucket = 64 final buckets
#define NSBMAX 64              // supports N <= 131072
#define P_CHUNK 2048           // edges per partition block
#define BPS 35                 // pass-2 blocks per SB
#define SBCAP (BPS * P_CHUNK)  // slots per SB in sbdata

typedef unsigned short ushort_t;
typedef unsigned int uint_t;

#define LO16(u) __uint_as_float((u) << 16)
#define HI16(u) __uint_as_float((u) & 0xffff0000u)

// fold across the 4 edge slots (lane bits 4..5) -- R3-proven edge1 shape
#define FOLDQ4(x) { x += __shfl_xor(x, 16, 64); x += __shfl_xor(x, 32, 64); }
// fold across all 64 lanes (leaves the TOTAL in every lane -- lane-uniform!)
#define FOLD64(x) { x += __shfl_xor(x, 1, 64); x += __shfl_xor(x, 2, 64); x += __shfl_xor(x, 4, 64); \
                    x += __shfl_xor(x, 8, 64); x += __shfl_xor(x, 16, 64); x += __shfl_xor(x, 32, 64); }

static __device__ __forceinline__ ushort_t f2bf(float f) {
    uint_t u = __float_as_uint(f);
    u = (u + 0x7FFFu + ((u >> 16) & 1u)) >> 16; // RNE
    return (ushort_t)u;
}
// pack {A=exp(e), B=exp(0.2e)} as bf16x2: A in low 16, B in high 16
static __device__ __forceinline__ uint_t packAB(float e) {
    return (uint_t)f2bf(__expf(e)) | ((uint_t)f2bf(__expf(NEG_SLOPE * e)) << 16);
}

// ---------------- Layer-1 GEMM: h1 = x @ W1 (bf16 out), fused exp-tables -----
__global__ void gemm1_kernel(const float* __restrict__ x, const float* __restrict__ W1,
                             const float* __restrict__ a_src, const float* __restrict__ a_dst,
                             ushort_t* __restrict__ h1, uint_t* __restrict__ sp,
                             float* __restrict__ ed, int N) {
    __shared__ float xs[16][FIN]; // 8 KB
    int tid = threadIdx.x;
    int n0 = blockIdx.x * 16;
    for (int i = tid; i < 16 * FIN; i += 256) {
        int nn = n0 + (i >> 7);
        xs[i >> 7][i & 127] = (nn < N) ? x[(size_t)nn * FIN + (i & 127)] : 0.f;
    }
    __syncthreads();
    int wv = tid >> 6, j = tid & 63;
    int nb = wv << 2;
    float a0 = 0.f, a1 = 0.f, a2 = 0.f, a3 = 0.f;
#pragma unroll 2
    for (int k = 0; k < FIN; k += 4) {
        float w0 = W1[(k + 0) * F1 + j];
        float w1 = W1[(k + 1) * F1 + j];
        float w2 = W1[(k + 2) * F1 + j];
        float w3 = W1[(k + 3) * F1 + j];
        float4 x0 = *(const float4*)&xs[nb + 0][k];
        float4 x1 = *(const float4*)&xs[nb + 1][k];
        float4 x2 = *(const float4*)&xs[nb + 2][k];
        float4 x3 = *(const float4*)&xs[nb + 3][k];
        a0 = fmaf(x0.x, w0, fmaf(x0.y, w1, fmaf(x0.z, w2, fmaf(x0.w, w3, a0))));
        a1 = fmaf(x1.x, w0, fmaf(x1.y, w1, fmaf(x1.z, w2, fmaf(x1.w, w3, a1))));
        a2 = fmaf(x2.x, w0, fmaf(x2.y, w1, fmaf(x2.z, w2, fmaf(x2.w, w3, a2))));
        a3 = fmaf(x3.x, w0, fmaf(x3.y, w1, fmaf(x3.z, w2, fmaf(x3.w, w3, a3))));
    }
    float as = a_src[j], ad = a_dst[j];
    float av[4] = {a0, a1, a2, a3};
#pragma unroll
    for (int t = 0; t < 4; ++t) {
        int n = n0 + nb + t;
        if (n >= N) break;
        h1[(size_t)n * F1 + j] = f2bf(av[t]);
        float vs = av[t] * as;
        float vd = av[t] * ad;
#pragma unroll
        for (int off = 4; off >= 1; off >>= 1) {
            vs += __shfl_down(vs, off, 8);
            vd += __shfl_down(vd, off, 8);
        }
        if ((j & 7) == 0) {
            sp[n * H1 + (j >> 3)] = packAB(vs);
            ed[n * H1 + (j >> 3)] = vd;
        }
    }
}

// ---------------- init ------------------------------------------------------
__global__ void zerob_kernel(int* __restrict__ bcnt, int* __restrict__ boff,
                             int NB, float* __restrict__ pooled, int capg,
                             int* __restrict__ sbcnt, int nsb) {
    int t = blockIdx.x * blockDim.x + threadIdx.x;
    int stride = gridDim.x * blockDim.x;
    for (int i = t; i < NB; i += stride) {
        bcnt[i] = 0;
        if (capg) boff[i] = i * capg;
    }
    for (int i = t; i < nsb; i += stride) sbcnt[i] = 0;
    if (t == 0) pooled[0] = 0.f;
}

// ---------------- Pass 1: partition edges into super-buckets (coalesced) -----
__global__ void __launch_bounds__(256, 4)
part1_kernel(const int* __restrict__ ei, int E, int N,
             int* __restrict__ sbcnt, uint_t* __restrict__ sbdata) {
    __shared__ int hist[NSBMAX];
    __shared__ int loff[NSBMAX];
    __shared__ int lcur[NSBMAX];
    __shared__ int gb[NSBMAX];
    __shared__ uint_t buf[P_CHUNK];
    __shared__ unsigned char sbarr[P_CHUNK];
    int tid = threadIdx.x;
    int NSB = (N + ((1 << SB_SHIFT) - 1)) >> SB_SHIFT;
    for (int i = tid; i < NSB; i += 256) hist[i] = 0;
    __syncthreads();
    int EN = E + N;
    int base = blockIdx.x * P_CHUNK;
    int m = EN - base; if (m > P_CHUNK) m = P_CHUNK;
    int t0 = base + tid * 8;
    int s[8], d[8];
    bool fast = (t0 + 8 <= E) && ((E & 3) == 0);
    if (fast) {
        int4 a = *(const int4*)&ei[t0];
        int4 b = *(const int4*)&ei[t0 + 4];
        s[0]=a.x; s[1]=a.y; s[2]=a.z; s[3]=a.w; s[4]=b.x; s[5]=b.y; s[6]=b.z; s[7]=b.w;
        int4 c = *(const int4*)&ei[E + t0];
        int4 e2 = *(const int4*)&ei[E + t0 + 4];
        d[0]=c.x; d[1]=c.y; d[2]=c.z; d[3]=c.w; d[4]=e2.x; d[5]=e2.y; d[6]=e2.z; d[7]=e2.w;
    } else {
#pragma unroll
        for (int r = 0; r < 8; ++r) {
            int t = t0 + r;
            if (t < EN) {
                if (t < E) { s[r] = ei[t]; d[r] = ei[E + t]; }
                else       { s[r] = d[r] = t - E; }
            } else d[r] = -1;
        }
    }
#pragma unroll
    for (int r = 0; r < 8; ++r)
        if (d[r] >= 0) atomicAdd(&hist[d[r] >> SB_SHIFT], 1);
    __syncthreads();
    if (tid < 64) {
        int v = (tid < NSB) ? hist[tid] : 0;
        int e = v;
#pragma unroll
        for (int o = 1; o < 64; o <<= 1) {
            int u = __shfl_up(e, o, 64);
            if (tid >= o) e += u;
        }
        e -= v; // exclusive prefix
        if (tid < NSB) {
            loff[tid] = e;
            lcur[tid] = e;
            gb[tid] = v ? atomicAdd(&sbcnt[tid], v) : 0;
        }
    }
    __syncthreads();
#pragma unroll
    for (int r = 0; r < 8; ++r)
        if (d[r] >= 0) {
            int sb = d[r] >> SB_SHIFT;
            int pos = atomicAdd(&lcur[sb], 1);
            buf[pos] = ((uint_t)s[r] << SB_SHIFT) | (uint_t)(d[r] & ((1 << SB_SHIFT) - 1));
            sbarr[pos] = (unsigned char)sb;
        }
    __syncthreads();
    for (int i = tid; i < m; i += 256) {
        int sb = sbarr[i];
        int idx = gb[sb] + (i - loff[sb]);
        if (idx < SBCAP)
            sbdata[(size_t)sb * SBCAP + idx] = buf[i];
    }
}

// ---------------- Pass 2: scatter within SB to final pk buckets (coalesced) --
__global__ void __launch_bounds__(256, 4)
part2_kernel(const uint_t* __restrict__ sbdata, const int* __restrict__ sbcnt,
             int* __restrict__ bcnt, const int* __restrict__ boff,
             uint_t* __restrict__ pk) {
    __shared__ int hist[64];
    __shared__ int loff[64];
    __shared__ int lcur[64];
    __shared__ int gb[64];
    __shared__ uint_t buf[P_CHUNK];
    int tid = threadIdx.x;
    int sb = blockIdx.x / BPS;
    int base = (blockIdx.x % BPS) * P_CHUNK;
    int cnt = sbcnt[sb];
    if (cnt > SBCAP) cnt = SBCAP;
    if (base >= cnt) return;
    int m = cnt - base; if (m > P_CHUNK) m = P_CHUNK;
    if (tid < 64) hist[tid] = 0;
    __syncthreads();
    const uint_t* src = sbdata + (size_t)sb * SBCAP + base;
    uint_t v[8];
#pragma unroll
    for (int r = 0; r < 8; ++r) {
        int i = tid + r * 256; // coalesced strided read
        if (i < m) {
            v[r] = src[i];
            atomicAdd(&hist[(v[r] >> 5) & 63], 1);
        }
    }
    __syncthreads();
    if (tid < 64) {
        int c = hist[tid];
        int e = c;
#pragma unroll
        for (int o = 1; o < 64; o <<= 1) {
            int u = __shfl_up(e, o, 64);
            if (tid >= o) e += u;
        }
        e -= c;
        loff[tid] = e;
        lcur[tid] = e;
        int bucket = (sb << 6) + tid;
        gb[tid] = c ? (boff[bucket] + atomicAdd(&bcnt[bucket], c)) : 0;
    }
    __syncthreads();
#pragma unroll
    for (int r = 0; r < 8; ++r) {
        int i = tid + r * 256;
        if (i < m) {
            int lb = (v[r] >> 5) & 63;
            int pos = atomicAdd(&lcur[lb], 1);
            buf[pos] = v[r];
        }
    }
    __syncthreads();
    for (int i = tid; i < m; i += 256) {
        uint_t u = buf[i];
        int lb = (u >> 5) & 63;
        int idx = gb[lb] + (i - loff[lb]);
        pk[idx] = ((u >> SB_SHIFT) << SHIFT) | (u & (BW - 1));
    }
}

// ---- exact-CSR fallback path (used only when ws_size too small for static) --
__global__ void bhist_kernel(const int* __restrict__ ei, int E, int N,
                             int* __restrict__ bcnt, int NB) {
    __shared__ int h[NBMAX];
    int tid = threadIdx.x;
    for (int i = tid; i < NB; i += 256) h[i] = 0;
    __syncthreads();
    int EN = E + N;
    int chunk = (EN + gridDim.x - 1) / gridDim.x;
    int e0 = blockIdx.x * chunk;
    int e1 = e0 + chunk; if (e1 > EN) e1 = EN;
    for (int t = e0 + tid; t < e1; t += 256) {
        int d = (t < E) ? ei[E + t] : (t - E);
        atomicAdd(&h[d >> SHIFT], 1);
    }
    __syncthreads();
    for (int i = tid; i < NB; i += 256)
        if (h[i]) atomicAdd(&bcnt[i], h[i]);
}

__global__ void bscan_kernel(const int* __restrict__ bcnt, int NB,
                             int* __restrict__ boff, int* __restrict__ bcur) {
    int lane = threadIdx.x; // 0..63
    int chunk = (NB + 63) >> 6;
    int lo = lane * chunk;
    int hi = lo + chunk; if (hi > NB) hi = NB;
    int sum = 0;
    for (int i = lo; i < hi; ++i) sum += bcnt[i];
    int e = sum;
#pragma unroll
    for (int o = 1; o < 64; o <<= 1) {
        int v = __shfl_up(e, o, 64);
        if (lane >= o) e += v;
    }
    e -= sum;
    int run = e;
    for (int i = lo; i < hi; ++i) {
        int c = bcnt[i];
        boff[i] = run;
        bcur[i] = run;
        run += c;
    }
}

__global__ void bscat_kernel(const int* __restrict__ ei, int E, int N,
                             int* __restrict__ bcur, uint_t* __restrict__ pk, int NB) {
    __shared__ int lh[NBMAX];
    __shared__ int lc[NBMAX];
    int tid = threadIdx.x;
    for (int i = tid; i < NB; i += 256) lh[i] = 0;
    __syncthreads();
    int EN = E + N;
    int chunk = (EN + gridDim.x - 1) / gridDim.x;
    int e0 = blockIdx.x * chunk;
    int e1 = e0 + chunk; if (e1 > EN) e1 = EN;
    for (int t = e0 + tid; t < e1; t += 256) {
        int d = (t < E) ? ei[E + t] : (t - E);
        atomicAdd(&lh[d >> SHIFT], 1);
    }
    __syncthreads();
    for (int i = tid; i < NB; i += 256) {
        int c = lh[i];
        lc[i] = c ? atomicAdd(&bcur[i], c) : 0;
    }
    __syncthreads();
    for (int t = e0 + tid; t < e1; t += 256) {
        int s, d;
        if (t < E) { s = ei[t]; d = ei[E + t]; } else { s = d = t - E; }
        int pos = atomicAdd(&lc[d >> SHIFT], 1);
        pk[pos] = ((uint_t)s << SHIFT) | (uint_t)(d & (BW - 1));
    }
}

// ---------------- Fused layer-1 edge pass + layer-2 GEMM ---------------------
// Gather body is the R3/R8-proven one (per-bucket launch, 4 slots, depth-1
// prefetch). R10-proven version (R11's build/epilogue rework regressed):
//  (a) a1 rows stay in LDS (no o1 materialization, -51 MB traffic),
//  (b) epilogue computes h2 = elu(a1+b1)@W2 and emits rec={packAB(vs), g.Wr}
//      + ed2 directly (gemm2 kernel removed),
//  (c) sorted src list written back over pk + per-dst CSR (loffg/ldegg) so
//      edge2 needs no LDS build at all.
__global__ void __launch_bounds__(256, 8)
edge1_fused(const int* __restrict__ bcnt, const int* __restrict__ boff,
            uint_t* __restrict__ pk,
            const uint_t* __restrict__ sp, const float* __restrict__ ed,
            const ushort_t* __restrict__ h1,
            const float* __restrict__ b1, const float* __restrict__ W2,
            const float* __restrict__ a_src2, const float* __restrict__ a_dst2,
            const float* __restrict__ Wr,
            uint2* __restrict__ rec, float* __restrict__ ed2,
            int* __restrict__ loffg, int* __restrict__ ldegg, int N) {
    int b = blockIdx.x;
    int d0 = b << SHIFT;
    int cnt = bcnt[b];
    int gbase = boff[b];
    int tid = threadIdx.x;
    int wv = tid >> 6;
    int L = tid & 63;
    int q = L >> 4;           // edge slot 0..3
    int c4 = (L & 15) << 2;   // channel base
    int hL = (L & 15) >> 1;   // head of channels c4..c4+3
    __shared__ int ldeg[BW], loff[BW], lcur[BW];
    __shared__ int lsrc[CAPL];
    __shared__ float a1s[BW][F1];   // 8 KB: this bucket's aggregated rows
    if (cnt <= CAPL) {
        if (tid < BW) ldeg[tid] = 0;
        __syncthreads();
        for (int k = tid; k < cnt; k += 256) atomicAdd(&ldeg[pk[gbase + k] & (BW - 1)], 1);
        __syncthreads();
        if (tid < BW) {
            int v = ldeg[tid];
            int e = v;
#pragma unroll
            for (int o = 1; o < BW; o <<= 1) {
                int u = __shfl_up(e, o, 64);
                if (tid >= o) e += u;
            }
            e -= v;
            loff[tid] = e;
            lcur[tid] = e;
        }
        __syncthreads();
        for (int k = tid; k < cnt; k += 256) {
            uint_t v = pk[gbase + k];
            int pos = atomicAdd(&lcur[v & (BW - 1)], 1);
            lsrc[pos] = (int)(v >> SHIFT);
        }
        __syncthreads();
        // writeback for edge2: pk becomes the dst-sorted src list; per-dst CSR
        for (int k = tid; k < cnt; k += 256) pk[gbase + k] = (uint_t)lsrc[k];
        if (tid < BW) {
            loffg[d0 + tid] = loff[tid];
            ldegg[d0 + tid] = ldeg[tid];
        }
        for (int ld = wv * 8; ld < wv * 8 + 8; ++ld) {
            int d = d0 + ld;
            if (d >= N) break;
            int st = loff[ld], en = st + ldeg[ld];
            float edv = ed[d * H1 + hL];
            float Ad = __expf(edv), Bd = __expf(NEG_SLOPE * edv);
            float ax = 0.f, ay = 0.f, az = 0.f, aw = 0.f, wsum = 0.f;
            uint_t U0, U1; uint2 V0, V1;
            {
                int i0 = st + q, i1 = st + 4 + q;
                bool ok0 = i0 < en, ok1 = i1 < en;
                int s0 = lsrc[ok0 ? i0 : st];   // st valid: self-loop => en>st
                int s1 = lsrc[ok1 ? i1 : st];
                uint_t u0 = sp[s0 * H1 + hL];
                uint_t u1 = sp[s1 * H1 + hL];
                V0 = *(const uint2*)(h1 + ((size_t)s0 << 6) + c4);
                V1 = *(const uint2*)(h1 + ((size_t)s1 << 6) + c4);
                U0 = ok0 ? u0 : 0u;
                U1 = ok1 ? u1 : 0u;
            }
            for (int k = st; k < en; k += 8) {
                uint_t N0, N1; uint2 P0, P1;
                {
                    int i0 = k + 8 + q, i1 = k + 12 + q;
                    bool ok0 = i0 < en, ok1 = i1 < en;
                    int s0 = lsrc[ok0 ? i0 : st];
                    int s1 = lsrc[ok1 ? i1 : st];
                    uint_t u0 = sp[s0 * H1 + hL];
                    uint_t u1 = sp[s1 * H1 + hL];
                    P0 = *(const uint2*)(h1 + ((size_t)s0 << 6) + c4);
                    P1 = *(const uint2*)(h1 + ((size_t)s1 << 6) + c4);
                    N0 = ok0 ? u0 : 0u;
                    N1 = ok1 ? u1 : 0u;
                }
                float w0 = fmaxf(LO16(U0) * Ad, HI16(U0) * Bd);
                float w1 = fmaxf(LO16(U1) * Ad, HI16(U1) * Bd);
                ax = fmaf(w0, LO16(V0.x), ax);
                ay = fmaf(w0, HI16(V0.x), ay);
                az = fmaf(w0, LO16(V0.y), az);
                aw = fmaf(w0, HI16(V0.y), aw);
                ax = fmaf(w1, LO16(V1.x), ax);
                ay = fmaf(w1, HI16(V1.x), ay);
                az = fmaf(w1, LO16(V1.y), az);
                aw = fmaf(w1, HI16(V1.y), aw);
                wsum += w0 + w1;
                U0 = N0; U1 = N1; V0 = P0; V1 = P1;
            }
            FOLDQ4(ax); FOLDQ4(ay); FOLDQ4(az); FOLDQ4(aw); FOLDQ4(wsum);
            if (q == 0) {
                float inv = 1.f / wsum;
                a1s[ld][c4 + 0] = ax * inv;
                a1s[ld][c4 + 1] = ay * inv;
                a1s[ld][c4 + 2] = az * inv;
                a1s[ld][c4 + 3] = aw * inv;
            }
        }
    } else {
        // statistically unreachable fallback: masked whole-bucket scan
        for (int ld = wv * 8; ld < wv * 8 + 8; ++ld) {
            int d = d0 + ld;
            if (d >= N) break;
            float edv = ed[d * H1 + hL];
            float Ad = __expf(edv), Bd = __expf(NEG_SLOPE * edv);
            float ax = 0.f, ay = 0.f, az = 0.f, aw = 0.f, wsum = 0.f;
            for (int k0 = 0; k0 < cnt; k0 += 4) {
                int idx = k0 + q;
                bool ok = idx < cnt;
                uint_t v = pk[gbase + (ok ? idx : 0)];
                int s = (int)(v >> SHIFT);
                bool m = ok && ((int)(v & (BW - 1)) == ld);
                uint_t u = sp[(uint_t)s * H1 + hL];
                float w = m ? fmaxf(LO16(u) * Ad, HI16(u) * Bd) : 0.f;
                uint2 hv = *(const uint2*)(h1 + ((size_t)s << 6) + c4);
                ax = fmaf(w, LO16(hv.x), ax);
                ay = fmaf(w, HI16(hv.x), ay);
                az = fmaf(w, LO16(hv.y), az);
                aw = fmaf(w, HI16(hv.y), aw);
                wsum += w;
            }
            FOLDQ4(ax); FOLDQ4(ay); FOLDQ4(az); FOLDQ4(aw); FOLDQ4(wsum);
            if (q == 0) {
                float inv = 1.f / wsum;
                a1s[ld][c4 + 0] = ax * inv;
                a1s[ld][c4 + 1] = ay * inv;
                a1s[ld][c4 + 2] = az * inv;
                a1s[ld][c4 + 3] = aw * inv;
            }
        }
    }
    // -------- fused layer-2 GEMM epilogue (replaces gemm2_kernel) --------
    int nd = N - d0; if (nd > BW) nd = BW;  // valid dsts in this bucket
    __syncthreads();
    for (int i = tid; i < BW * F1; i += 256) {
        int dd = i >> 6;
        if (dd < nd) {
            int k = i & 63;
            float v = a1s[dd][k] + b1[k];
            a1s[dd][k] = v > 0.f ? v : expm1f(v); // ELU
        }
    }
    __syncthreads();
    int half = tid >> 5, j = tid & 31;
#pragma unroll
    for (int pass = 0; pass < 4; ++pass) {
        int ld2 = half + (pass << 3);
        if (ld2 < nd) {
            float acc = 0.f;
#pragma unroll
            for (int k = 0; k < F1; ++k) acc = fmaf(a1s[ld2][k], W2[k * F2 + j], acc);
            float vs = acc * a_src2[j];
            float vd = acc * a_dst2[j];
            float vg = acc * Wr[j];
#pragma unroll
            for (int off = 16; off >= 1; off >>= 1) {
                vs += __shfl_down(vs, off, 32);
                vd += __shfl_down(vd, off, 32);
                vg += __shfl_down(vg, off, 32);
            }
            if (j == 0) {
                int d = d0 + ld2;
                uint2 r; r.x = packAB(vs); r.y = __float_as_uint(vg);
                rec[d] = r;
                ed2[d] = vd;
            }
        }
    }
}

// ---------------- Layer-2 edge pass: pure streaming gather -------------------
// pk holds dst-sorted src lists (written by edge1_fused); loffg/ldegg give the
// per-dst CSR. No LDS build: coalesced pk reads + 8-B rec gathers (800 KB,
// L2-resident). Fallback buckets (cnt > CAPL) kept raw -> masked scan.
__global__ void __launch_bounds__(256, 8)
edge2_gather(const int* __restrict__ bcnt, const int* __restrict__ boff,
             const uint_t* __restrict__ pk,
             const int* __restrict__ loffg, const int* __restrict__ ldegg,
             const uint2* __restrict__ rec, const float* __restrict__ ed2,
             const float* __restrict__ b2, const float* __restrict__ Wr,
             float* __restrict__ pooled, int N) {
    int b = blockIdx.x;
    int d0 = b << SHIFT;
    int cnt = bcnt[b];
    int gbase = boff[b];
    int tid = threadIdx.x;
    int wv = tid >> 6;
    int L = tid & 63;
    __shared__ float ls[4];
    float t0 = (L < F2) ? b2[L] * Wr[L] : 0.f;
    FOLD64(t0);
    float b2w = t0;          // dot(b2, Wr), identical on all lanes
    float part = 0.f;
    if (cnt <= CAPL) {
        for (int ld = wv * 8; ld < wv * 8 + 8; ++ld) {
            int d = d0 + ld;
            if (d >= N) break;
            int st = gbase + loffg[d];
            int dg = ldegg[d];
            float edv = ed2[d];
            float Ad = __expf(edv), Bd = __expf(NEG_SLOPE * edv);
            float acc = 0.f, wsm = 0.f;
            for (int k = 0; k < dg; k += 64) {
                int i = k + L;
                bool ok = i < dg;
                int s = (int)pk[st + (ok ? i : 0)];
                uint2 r = rec[s];
                float w = ok ? fmaxf(LO16(r.x) * Ad, HI16(r.x) * Bd) : 0.f;
                acc = fmaf(w, __uint_as_float(r.y), acc);
                wsm += w;
            }
            FOLD64(acc); FOLD64(wsm);
            part += acc / wsm + b2w;   // FOLD64 left totals in EVERY lane
        }
    } else {
        // raw-pk masked scan (pk left in original packed format for this bucket)
        for (int ld = wv * 8; ld < wv * 8 + 8; ++ld) {
            int d = d0 + ld;
            if (d >= N) break;
            float edv = ed2[d];
            float Ad = __expf(edv), Bd = __expf(NEG_SLOPE * edv);
            float acc = 0.f, wsm = 0.f;
            for (int k0 = 0; k0 < cnt; k0 += 64) {
                int i = k0 + L;
                bool ok = i < cnt;
                uint_t v = pk[gbase + (ok ? i : 0)];
                int s = (int)(v >> SHIFT);
                bool mm = ok && ((int)(v & (BW - 1)) == ld);
                uint2 r = rec[s];
                float w = mm ? fmaxf(LO16(r.x) * Ad, HI16(r.x) * Bd) : 0.f;
                acc = fmaf(w, __uint_as_float(r.y), acc);
                wsm += w;
            }
            FOLD64(acc); FOLD64(wsm);
            part += acc / wsm + b2w;
        }
    }
    // part is LANE-UNIFORM (FOLD64 totals) -- take lane 0 only.
    // R9 BUG: an extra 64-lane shfl_down sum here counted each dst 64x.
    if (L == 0) ls[wv] = part;
    __syncthreads();
    if (tid == 0) atomicAdd(pooled, ls[0] + ls[1] + ls[2] + ls[3]);
}

__global__ void final_kernel(const float* __restrict__ pooled, const float* __restrict__ br,
                             float* __restrict__ out) {
    if (threadIdx.x == 0 && blockIdx.x == 0) out[0] = pooled[0] + br[0];
}

static inline size_t al128(size_t v) { return (v + 127) & ~(size_t)127; }

extern "C" void kernel_launch(void* const* d_in, const int* in_sizes, int n_in,
                              void* d_out, int out_size, void* d_ws, size_t ws_size,
                              hipStream_t stream) {
    const float* x    = (const float*)d_in[0];
    const int*   ei   = (const int*)d_in[1];
    const float* W1   = (const float*)d_in[2];
    const float* a_s1 = (const float*)d_in[3];
    const float* a_d1 = (const float*)d_in[4];
    const float* b1   = (const float*)d_in[5];
    const float* W2   = (const float*)d_in[6];
    const float* a_s2 = (const float*)d_in[7];
    const float* a_d2 = (const float*)d_in[8];
    const float* b2   = (const float*)d_in[9];
    const float* Wr   = (const float*)d_in[10];
    const float* br   = (const float*)d_in[11];
    float* out = (float*)d_out;

    int N = in_sizes[0] / FIN;
    int E = in_sizes[1] / 2;
    size_t n = (size_t)N;
    int NB = (N + BW - 1) >> SHIFT;
    int NSB = (N + ((1 << SB_SHIFT) - 1)) >> SB_SHIFT;

    // workspace layout (bytes); all hot arrays 128-B aligned.
    // CRITICAL: h1 rows are 128 B and gathered randomly -- h1 base MUST be
    // 128-aligned or every row straddles two cache lines (R4: FETCH +64%).
    // The former o1 region (256N bytes) is now pure scratch: sbdata lives
    // there during part1/part2 (dead after), then rec/ed2/loffg/ldegg are
    // written there by edge1_fused (disjoint lifetimes, overlapping addrs ok).
    char* ws = (char*)d_ws;
    size_t off_scr = 0;                                   // 256N scratch
    size_t off_sp1 = al128(off_scr + n * 256);            // 32N + 32
    size_t off_ed1 = al128(off_sp1 + n * 32 + 32);        // 32N
    size_t off_h1  = al128(off_ed1 + n * 32);             // 128N + 128
    size_t off_pk  = al128(off_h1 + n * 128 + 128);
    uint_t*   sp1  = (uint_t*)(ws + off_sp1);
    float*    ed1  = (float*)(ws + off_ed1);
    ushort_t* h1   = (ushort_t*)(ws + off_h1);
    uint_t*   pk   = (uint_t*)(ws + off_pk);
    size_t pk_static = (size_t)NB * CAP_G * 4;            // ~17.6 MB
    size_t pk_exact  = (size_t)(E + N) * 4;               // ~13.2 MB
    // scratch-region tenants:
    uint_t* sbdata = (uint_t*)(ws + off_scr);             // part1/part2 only
    size_t off_rec  = off_scr;                            // 8*NB*BW
    size_t off_ed2  = al128(off_rec + (size_t)NB * BW * 8);
    size_t off_lofg = al128(off_ed2 + (size_t)NB * BW * 4);
    size_t off_ldgg = al128(off_lofg + (size_t)NB * BW * 4);
    uint2* rec   = (uint2*)(ws + off_rec);
    float* ed2   = (float*)(ws + off_ed2);
    int*   loffg = (int*)(ws + off_lofg);
    int*   ldegg = (int*)(ws + off_ldgg);
    bool use_static = (NSB <= NSBMAX) &&
                      ((size_t)NSB * SBCAP * 4 <= n * 256) &&
                      (off_ldgg + (size_t)NB * BW * 4 <= n * 256) &&
                      (ws_size >= off_pk + pk_static + (size_t)NBMAX * 16 +
                                  (size_t)NSBMAX * 4 + 128);
    char* tail = ws + off_pk + (use_static ? pk_static : pk_exact);
    int*      bcnt  = (int*)tail;                         // NBMAX int
    int*      boff  = (int*)(tail + NBMAX * 4);           // NBMAX int
    int*      bcur  = (int*)(tail + NBMAX * 8);           // NBMAX int
    int*      sbcnt = (int*)(tail + NBMAX * 12);          // NSBMAX int
    float*  pooled  = (float*)(tail + NBMAX * 12 + NSBMAX * 4); // 1 f32

    zerob_kernel<<<8, 256, 0, stream>>>(bcnt, boff, NB, pooled,
                                        use_static ? CAP_G : 0, sbcnt, NSB);
    if (use_static) {
        int EN = E + N;
        int G1 = (EN + P_CHUNK - 1) / P_CHUNK;
        part1_kernel<<<G1, 256, 0, stream>>>(ei, E, N, sbcnt, sbdata);
        part2_kernel<<<NSB * BPS, 256, 0, stream>>>(sbdata, sbcnt, bcnt, boff, pk);
        gemm1_kernel<<<(N + 15) / 16, 256, 0, stream>>>(x, W1, a_s1, a_d1, h1, sp1, ed1, N);
    } else {
        gemm1_kernel<<<(N + 15) / 16, 256, 0, stream>>>(x, W1, a_s1, a_d1, h1, sp1, ed1, N);
        bhist_kernel<<<256, 256, 0, stream>>>(ei, E, N, bcnt, NB);
        bscan_kernel<<<1, 64, 0, stream>>>(bcnt, NB, boff, bcur);
        bscat_kernel<<<256, 256, 0, stream>>>(ei, E, N, bcur, pk, NB);
    }
    edge1_fused<<<NB, 256, 0, stream>>>(bcnt, boff, pk, sp1, ed1, h1,
                                        b1, W2, a_s2, a_d2, Wr,
                                        rec, ed2, loffg, ldegg, N);
    edge2_gather<<<NB, 256, 0, stream>>>(bcnt, boff, pk, loffg, ldegg,
                                         rec, ed2, b2, Wr, pooled, N);
    final_kernel<<<1, 64, 0, stream>>>(pooled, br, out);
}